// Round 1
// baseline (104152.747 us; speedup 1.0000x reference)
//
#include <hip/hip_runtime.h>
#include <math.h>

#define TT   1024
#define BB   64
#define HH   512
#define NBLK 256
#define NTHR 512

// output layout: out[T][B][H] | h_n[L][B][H] | c_n[L][B][H]
#define HN_OFF ((size_t)TT * BB * HH)          // 33,554,432
#define CN_OFF (HN_OFF + (size_t)2 * BB * HH)  // +65,536

__device__ inline float sigm(float v) {
    return 1.0f / (1.0f + __expf(-v));
}

__device__ inline float tanh_fast(float v) {
    // tanh(x) = 1 - 2/(exp(2x)+1); saturates correctly for |x| large
    const float e = __expf(2.0f * v);
    return 1.0f - 2.0f / (e + 1.0f);
}

// Two-level grid barrier: 16 groups x 16 blocks -> root. Monotonic counters
// (no reset), agent-scope atomics. Counters zeroed by hipMemsetAsync before
// launch. Max skew between blocks is 1 step -> hbuf is double-buffered.
__device__ inline void grid_barrier(unsigned* gbar, unsigned* groot,
                                    unsigned barIdx, int bid)
{
    __syncthreads();
    if (threadIdx.x == 0) {
        __threadfence();  // release all global writes of this block
        const int g = bid & 15;
        const unsigned old = __hip_atomic_fetch_add(
            &gbar[g * 16], 1u, __ATOMIC_ACQ_REL, __HIP_MEMORY_SCOPE_AGENT);
        if (old == barIdx * 16u + 15u) {
            // last of my group: promote to root
            __hip_atomic_fetch_add(groot, 1u, __ATOMIC_ACQ_REL,
                                   __HIP_MEMORY_SCOPE_AGENT);
        }
        const unsigned tgt = (barIdx + 1u) * 16u;
        while (__hip_atomic_load(groot, __ATOMIC_ACQUIRE,
                                 __HIP_MEMORY_SCOPE_AGENT) < tgt) {
            __builtin_amdgcn_s_sleep(2);
        }
        __threadfence();  // acquire: invalidate L1 before re-reading state
    }
    __syncthreads();
}

extern "C" __global__ void __launch_bounds__(NTHR)
lstm_persist(const float* __restrict__ x,
             const float* __restrict__ h0,
             const float* __restrict__ c0,
             const float* __restrict__ Wih,
             const float* __restrict__ Whh,
             const float* __restrict__ bih,
             const float* __restrict__ bhh,
             float* __restrict__ out,
             float* __restrict__ hseq,   // [T][H][B] layer-0 output (ws)
             float* __restrict__ hbuf,   // [2][H][B] double-buffered h (ws)
             unsigned* __restrict__ gbar,
             unsigned* __restrict__ groot)
{
    // xtile: per-wave transpose tile of x: [b][k_local], pad 33 (2-way max)
    __shared__ float xtile[4][64][33];
    __shared__ float red[8][8][64];

    const int tid  = threadIdx.x;
    const int w    = tid >> 6;    // wave 0..7
    const int lane = tid & 63;    // lane == batch index
    const int bid  = blockIdx.x;
    if (bid >= NBLK) return;
    const int hk0  = bid << 1;    // this block owns hidden cols hk0, hk0+1

    unsigned barIdx = 0;
    float creg0 = 0.0f, creg1 = 0.0f;  // live in wave 0 only

    for (int l = 0; l < 2; ++l) {
        const float* WihL = Wih + (size_t)l * (4 * HH) * HH;
        const float* WhhL = Whh + (size_t)l * (4 * HH) * HH;
        const float* bihL = bih + l * (4 * HH);
        const float* bhhL = bhh + l * (4 * HH);

        if (w == 0) {
            // init h state (hbuf buffer 0) and c registers from h0/c0
            const float* h0L = h0 + (size_t)l * BB * HH;
            const float* c0L = c0 + (size_t)l * BB * HH;
            hbuf[(hk0 + 0) * BB + lane] = h0L[(size_t)lane * HH + hk0 + 0];
            hbuf[(hk0 + 1) * BB + lane] = h0L[(size_t)lane * HH + hk0 + 1];
            creg0 = c0L[(size_t)lane * HH + hk0 + 0];
            creg1 = c0L[(size_t)lane * HH + hk0 + 1];
        }
        grid_barrier(gbar, groot, barIdx, bid); ++barIdx;

        for (int t = 0; t < TT; ++t) {
            const int cur = t & 1;
            const int nxt = cur ^ 1;

            float acc[8];
            #pragma unroll
            for (int rr = 0; rr < 8; ++rr) acc[rr] = 0.0f;

            // gate row for rr: r = (rr>>1)*512 + hk0 + (rr&1)
            if (w < 4) {
                // input part: cols [w*128, w*128+128) of W_ih
                if (l == 0) {
                    // x is [t][b][k]: transpose through LDS, 32-k chunks
                    const int kl = lane & 31;
                    const int bs = lane >> 5;
                    #pragma unroll 1
                    for (int ch = 0; ch < 4; ++ch) {
                        const int kb = (w << 7) + (ch << 5);
                        #pragma unroll
                        for (int bb = 0; bb < 32; ++bb) {
                            const int be = (bb << 1) + bs;
                            xtile[w][be][kl] =
                                x[((size_t)t * BB + be) * HH + kb + kl];
                        }
                        #pragma unroll 8
                        for (int kk = 0; kk < 32; ++kk) {
                            const float zv = xtile[w][lane][kk];
                            const int kc = kb + kk;
                            #pragma unroll
                            for (int rr = 0; rr < 8; ++rr)
                                acc[rr] = fmaf(zv,
                                    WihL[(size_t)(((rr >> 1) << 9) + hk0 + (rr & 1)) * HH + kc],
                                    acc[rr]);
                        }
                    }
                } else {
                    // layer-1 input from hseq [t][k][b]: already coalesced
                    const float* hs = hseq + (size_t)t * HH * BB;
                    const int kb = w << 7;
                    #pragma unroll 8
                    for (int j = 0; j < 128; ++j) {
                        const int kc = kb + j;
                        const float zv = hs[kc * BB + lane];
                        #pragma unroll
                        for (int rr = 0; rr < 8; ++rr)
                            acc[rr] = fmaf(zv,
                                WihL[(size_t)(((rr >> 1) << 9) + hk0 + (rr & 1)) * HH + kc],
                                acc[rr]);
                    }
                }
            } else {
                // recurrent part: cols [(w-4)*128, ...) of W_hh
                const int kb = (w - 4) << 7;
                const float* hb = hbuf + (size_t)cur * HH * BB;
                #pragma unroll 8
                for (int j = 0; j < 128; ++j) {
                    const int kc = kb + j;
                    const float zv = hb[kc * BB + lane];
                    #pragma unroll
                    for (int rr = 0; rr < 8; ++rr)
                        acc[rr] = fmaf(zv,
                            WhhL[(size_t)(((rr >> 1) << 9) + hk0 + (rr & 1)) * HH + kc],
                            acc[rr]);
                }
            }

            // reduce 8 wave-partials through LDS
            #pragma unroll
            for (int rr = 0; rr < 8; ++rr) red[w][rr][lane] = acc[rr];
            __syncthreads();

            if (w == 0) {
                float g[8];
                #pragma unroll
                for (int rr = 0; rr < 8; ++rr) {
                    const int r = ((rr >> 1) << 9) + hk0 + (rr & 1);
                    float s = bihL[r] + bhhL[r];
                    #pragma unroll
                    for (int ww = 0; ww < 8; ++ww) s += red[ww][rr][lane];
                    g[rr] = s;
                }
                #pragma unroll
                for (int which = 0; which < 2; ++which) {
                    const float ig = sigm(g[0 + which]);
                    const float fg = sigm(g[2 + which]);
                    const float gg = tanh_fast(g[4 + which]);
                    const float og = sigm(g[6 + which]);
                    const float c_old = which ? creg1 : creg0;
                    const float cn = fg * c_old + ig * gg;
                    const float hn = og * tanh_fast(cn);
                    if (which) creg1 = cn; else creg0 = cn;
                    const int hk = hk0 + which;
                    hbuf[((size_t)nxt * HH + hk) * BB + lane] = hn;
                    if (l == 0) {
                        hseq[((size_t)t * HH + hk) * BB + lane] = hn;
                    } else {
                        out[((size_t)t * BB + lane) * HH + hk] = hn;
                    }
                    if (t == TT - 1) {
                        out[HN_OFF + ((size_t)l * BB + lane) * HH + hk] = hn;
                        out[CN_OFF + ((size_t)l * BB + lane) * HH + hk] = cn;
                    }
                }
            }
            grid_barrier(gbar, groot, barIdx, bid); ++barIdx;
        }
    }
}

extern "C" void kernel_launch(void* const* d_in, const int* in_sizes, int n_in,
                              void* d_out, int out_size, void* d_ws, size_t ws_size,
                              hipStream_t stream)
{
    (void)in_sizes; (void)n_in; (void)out_size; (void)ws_size;
    const float* x   = (const float*)d_in[0];
    const float* h0  = (const float*)d_in[1];
    const float* c0  = (const float*)d_in[2];
    const float* Wih = (const float*)d_in[3];
    const float* Whh = (const float*)d_in[4];
    const float* bih = (const float*)d_in[5];
    const float* bhh = (const float*)d_in[6];
    float* out = (float*)d_out;

    // ws layout: hseq [T][H][B] fp32 (128 MB) | hbuf [2][H][B] | barrier ctrs
    float* hseq = (float*)d_ws;
    float* hbuf = hseq + (size_t)TT * HH * BB;
    unsigned* gbar  = (unsigned*)(hbuf + (size_t)2 * HH * BB);
    unsigned* groot = gbar + 256;

    // barrier counters must start at 0 (ws is poisoned 0xAA each call)
    hipMemsetAsync(gbar, 0, (256 + 64) * sizeof(unsigned), stream);

    void* args[] = {(void*)&x, (void*)&h0, (void*)&c0, (void*)&Wih,
                    (void*)&Whh, (void*)&bih, (void*)&bhh, (void*)&out,
                    (void*)&hseq, (void*)&hbuf, (void*)&gbar, (void*)&groot};
    hipLaunchCooperativeKernel((void*)lstm_persist, dim3(NBLK), dim3(NTHR),
                               args, 0, stream);
}

// Round 2
// 73262.701 us; speedup vs baseline: 1.4216x; 1.4216x over previous
//
#include <hip/hip_runtime.h>
#include <math.h>

#define TT 1024
#define BB 64
#define HH 512
#define G4 2048            // 4*HH
#define NBLK 256
#define NTHR 512
#define KH (HH * BB)       // elements in one [512][64] slab = 32768

// out layout: seq [T][B][H] | h_n [L][B][H] | c_n [L][B][H]
#define HN_OFF ((size_t)TT * BB * HH)
#define CN_OFF (HN_OFF + (size_t)2 * BB * HH)

__device__ inline float sigm(float v) {
    return 1.0f / (1.0f + __expf(-v));
}
__device__ inline float tanh_fast(float v) {
    const float e = __expf(2.0f * v);
    return 1.0f - 2.0f / (e + 1.0f);
}

// ---------------- phase A: transpose x [T][B][K] -> xT [T][K][B] ------------
extern "C" __global__ void __launch_bounds__(256)
xpose(const float* __restrict__ x, float* __restrict__ xT)
{
    __shared__ float tile[64][65];
    const int t   = blockIdx.x;        // 0..1023
    const int kc  = blockIdx.y << 6;   // 0,64,...,448
    const int tid = threadIdx.x;

    const int kk = tid & 63;
    const int b0 = tid >> 6;           // 0..3
    const float* xp = x + (size_t)t * BB * HH;
    #pragma unroll
    for (int i = 0; i < 16; ++i) {
        const int b = b0 + (i << 2);
        tile[b][kk] = xp[(size_t)b * HH + kc + kk];
    }
    __syncthreads();
    const int b  = tid & 63;
    const int k0 = tid >> 6;
    float* xo = xT + (size_t)t * KH + (size_t)kc * BB;
    #pragma unroll
    for (int i = 0; i < 16; ++i) {
        const int kl = k0 + (i << 2);
        xo[kl * BB + b] = tile[b][kl];
    }
}

// ---------------- two-level grid barrier (round-1 proven) -------------------
__device__ inline void grid_barrier(unsigned* gbar, unsigned* groot,
                                    unsigned barIdx, int bid)
{
    __syncthreads();
    if (threadIdx.x == 0) {
        __threadfence();
        const int g = bid & 15;
        const unsigned old = __hip_atomic_fetch_add(
            &gbar[g * 16], 1u, __ATOMIC_ACQ_REL, __HIP_MEMORY_SCOPE_AGENT);
        if (old == barIdx * 16u + 15u) {
            __hip_atomic_fetch_add(groot, 1u, __ATOMIC_ACQ_REL,
                                   __HIP_MEMORY_SCOPE_AGENT);
        }
        const unsigned tgt = (barIdx + 1u) * 16u;
        while (__hip_atomic_load(groot, __ATOMIC_ACQUIRE,
                                 __HIP_MEMORY_SCOPE_AGENT) < tgt) {
            __builtin_amdgcn_s_sleep(2);
        }
        __threadfence();
    }
    __syncthreads();
}

// ---------------- phase B: pipelined persistent scan ------------------------
// 256 blocks x 8 waves. Block owns 2 hidden units per layer (8 gate rows each).
// Barrier-step s: L0 computes t0=s (s<TT), L1 computes t1=s-1 (s>=1).
// Wave roles (grp = w>>1): 0: L0 input-proj (xT), 1: L0 recurrent (h0buf),
//                          2: L1 input-proj (h0buf), 3: L1 recurrent (h1buf).
// kbase = (w&1)*256. Wave 0 does gate math for both layers (single writer).
extern "C" __global__ void __launch_bounds__(NTHR)
lstm_scan(const float* __restrict__ h0,
          const float* __restrict__ c0,
          const float* __restrict__ Wih,
          const float* __restrict__ Whh,
          const float* __restrict__ bih,
          const float* __restrict__ bhh,
          const float* __restrict__ xT,
          float* __restrict__ out,
          float* __restrict__ h0buf,   // [2][512][64]
          float* __restrict__ h1buf,   // [2][512][64]
          unsigned* __restrict__ gbar,
          unsigned* __restrict__ groot)
{
    __shared__ float red[8][8][64];    // [wave][row][batch] partials, 16 KB

    const int tid  = threadIdx.x;
    const int lane = tid & 63;                                   // batch
    const int w    = __builtin_amdgcn_readfirstlane(tid >> 6);   // wave 0..7
    const int bid  = blockIdx.x;
    const int hk0  = bid << 1;         // hidden units hk0, hk0+1

    const int kbase = (w & 1) << 8;    // 0 or 256
    const int grp   = w >> 1;          // source group

    const float* Wbase;
    if      (grp == 0) Wbase = Wih;
    else if (grp == 1) Wbase = Whh;
    else if (grp == 2) Wbase = Wih + (size_t)G4 * HH;
    else               Wbase = Whh + (size_t)G4 * HH;

    const float* Wrow[8];
    #pragma unroll
    for (int rr = 0; rr < 8; ++rr) {
        const int row = ((rr >> 1) << 9) + hk0 + (rr & 1);
        Wrow[rr] = Wbase + (size_t)row * HH + kbase;
    }

    float c0reg[2] = {0.f, 0.f}, c1reg[2] = {0.f, 0.f};
    float b0s[8], b1s[8];
    if (w == 0) {
        #pragma unroll
        for (int u = 0; u < 2; ++u) {
            const int hk = hk0 + u;
            h0buf[hk * BB + lane] = h0[(size_t)lane * HH + hk];
            h1buf[hk * BB + lane] = h0[(size_t)(BB + lane) * HH + hk];
            c0reg[u] = c0[(size_t)lane * HH + hk];
            c1reg[u] = c0[(size_t)(BB + lane) * HH + hk];
        }
        #pragma unroll
        for (int rr = 0; rr < 8; ++rr) {
            const int row = ((rr >> 1) << 9) + hk0 + (rr & 1);
            b0s[rr] = bih[row] + bhh[row];
            b1s[rr] = bih[G4 + row] + bhh[G4 + row];
        }
    }

    unsigned barIdx = 0;
    grid_barrier(gbar, groot, barIdx, bid); ++barIdx;

    for (int s = 0; s <= TT; ++s) {
        const float* act;
        if (grp == 0) {
            const int t0 = (s < TT) ? s : (TT - 1);
            act = xT + (size_t)t0 * KH + (size_t)kbase * BB;
        } else if (grp <= 2) {
            act = h0buf + (size_t)(s & 1) * KH + (size_t)kbase * BB;
        } else {
            act = h1buf + (size_t)((s + 1) & 1) * KH + (size_t)kbase * BB;
        }

        float acc[8];
        #pragma unroll
        for (int rr = 0; rr < 8; ++rr) acc[rr] = 0.0f;

        #pragma unroll 2
        for (int j = 0; j < 256; j += 4) {
            const float a0 = act[(j + 0) * BB + lane];
            const float a1 = act[(j + 1) * BB + lane];
            const float a2 = act[(j + 2) * BB + lane];
            const float a3 = act[(j + 3) * BB + lane];
            #pragma unroll
            for (int rr = 0; rr < 8; ++rr) {
                const float4 wv = *(const float4*)(Wrow[rr] + j);
                acc[rr] = fmaf(a3, wv.w,
                           fmaf(a2, wv.z,
                            fmaf(a1, wv.y,
                             fmaf(a0, wv.x, acc[rr]))));
            }
        }

        #pragma unroll
        for (int rr = 0; rr < 8; ++rr) red[w][rr][lane] = acc[rr];
        __syncthreads();

        if (w == 0) {
            if (s < TT) {   // layer 0, t0 = s
                float g[8];
                #pragma unroll
                for (int rr = 0; rr < 8; ++rr)
                    g[rr] = b0s[rr] + red[0][rr][lane] + red[1][rr][lane]
                                    + red[2][rr][lane] + red[3][rr][lane];
                #pragma unroll
                for (int u = 0; u < 2; ++u) {
                    const float ig = sigm(g[0 + u]);
                    const float fg = sigm(g[2 + u]);
                    const float gg = tanh_fast(g[4 + u]);
                    const float og = sigm(g[6 + u]);
                    const float cn = fg * c0reg[u] + ig * gg;
                    const float hn = og * tanh_fast(cn);
                    c0reg[u] = cn;
                    const int hk = hk0 + u;
                    h0buf[(size_t)((s + 1) & 1) * KH + hk * BB + lane] = hn;
                    if (s == TT - 1) {
                        out[HN_OFF + (size_t)lane * HH + hk] = hn;
                        out[CN_OFF + (size_t)lane * HH + hk] = cn;
                    }
                }
            }
            if (s >= 1) {   // layer 1, t1 = s-1
                const int t1 = s - 1;
                float g[8];
                #pragma unroll
                for (int rr = 0; rr < 8; ++rr)
                    g[rr] = b1s[rr] + red[4][rr][lane] + red[5][rr][lane]
                                    + red[6][rr][lane] + red[7][rr][lane];
                #pragma unroll
                for (int u = 0; u < 2; ++u) {
                    const float ig = sigm(g[0 + u]);
                    const float fg = sigm(g[2 + u]);
                    const float gg = tanh_fast(g[4 + u]);
                    const float og = sigm(g[6 + u]);
                    const float cn = fg * c1reg[u] + ig * gg;
                    const float hn = og * tanh_fast(cn);
                    c1reg[u] = cn;
                    const int hk = hk0 + u;
                    h1buf[(size_t)(s & 1) * KH + hk * BB + lane] = hn;
                    out[(size_t)t1 * BB * HH + (size_t)lane * HH + hk] = hn;
                    if (t1 == TT - 1) {
                        out[HN_OFF + (size_t)(BB + lane) * HH + hk] = hn;
                        out[CN_OFF + (size_t)(BB + lane) * HH + hk] = cn;
                    }
                }
            }
        }
        grid_barrier(gbar, groot, barIdx, bid); ++barIdx;
    }
}

// ---------------------------------------------------------------------------
extern "C" void kernel_launch(void* const* d_in, const int* in_sizes, int n_in,
                              void* d_out, int out_size, void* d_ws, size_t ws_size,
                              hipStream_t stream)
{
    (void)in_sizes; (void)n_in; (void)out_size; (void)ws_size;
    const float* x   = (const float*)d_in[0];
    const float* h0  = (const float*)d_in[1];
    const float* c0  = (const float*)d_in[2];
    const float* Wih = (const float*)d_in[3];
    const float* Whh = (const float*)d_in[4];
    const float* bih = (const float*)d_in[5];
    const float* bhh = (const float*)d_in[6];
    float* out = (float*)d_out;

    // ws: xT [T][512][64] (128 MB) | h0buf [2][512][64] | h1buf | barrier ctrs
    float* xT    = (float*)d_ws;
    float* h0buf = xT + (size_t)TT * KH;
    float* h1buf = h0buf + (size_t)2 * KH;
    unsigned* gbar  = (unsigned*)(h1buf + (size_t)2 * KH);
    unsigned* groot = gbar + 256;

    hipMemsetAsync(gbar, 0, (256 + 64) * sizeof(unsigned), stream);

    xpose<<<dim3(TT, 8), 256, 0, stream>>>(x, xT);

    void* args[] = {(void*)&h0, (void*)&c0, (void*)&Wih, (void*)&Whh,
                    (void*)&bih, (void*)&bhh, (void*)&xT, (void*)&out,
                    (void*)&h0buf, (void*)&h1buf, (void*)&gbar, (void*)&groot};
    hipLaunchCooperativeKernel((void*)lstm_scan, dim3(NBLK), dim3(NTHR),
                               args, 0, stream);
}

// Round 3
// 38374.591 us; speedup vs baseline: 2.7141x; 1.9091x over previous
//
#include <hip/hip_runtime.h>
#include <math.h>

#define TT 1024
#define BB 64
#define HH 512
#define G4 2048            // 4*HH
#define NBLK 256
#define NTHR 512
#define KH (HH * BB)       // one [512][64] slab = 32768 elems

// out layout: seq [T][B][H] | h_n [L][B][H] | c_n [L][B][H]
#define HN_OFF ((size_t)TT * BB * HH)
#define CN_OFF (HN_OFF + (size_t)2 * BB * HH)

__device__ inline float sigm(float v) {
    return 1.0f / (1.0f + __expf(-v));
}
__device__ inline float tanh_fast(float v) {
    const float e = __expf(2.0f * v);
    return 1.0f - 2.0f / (e + 1.0f);
}

// Coherent (L2-bypassing, sc1) store: lands at the L3 coherence point so
// other XCDs can see it after their per-step buffer_inv. No wbl2 needed.
__device__ inline void store_coh(float* p, float v) {
    __hip_atomic_store(p, v, __ATOMIC_RELAXED, __HIP_MEMORY_SCOPE_AGENT);
}

// ---------------- phase A: transpose x [T][B][K] -> xT [T][K][B] ------------
extern "C" __global__ void __launch_bounds__(256)
xpose(const float* __restrict__ x, float* __restrict__ xT)
{
    __shared__ float tile[64][65];
    const int t   = blockIdx.x;
    const int kc  = blockIdx.y << 6;
    const int tid = threadIdx.x;

    const int kk = tid & 63;
    const int b0 = tid >> 6;
    const float* xp = x + (size_t)t * BB * HH;
    #pragma unroll
    for (int i = 0; i < 16; ++i) {
        const int b = b0 + (i << 2);
        tile[b][kk] = xp[(size_t)b * HH + kc + kk];
    }
    __syncthreads();
    const int b  = tid & 63;
    const int k0 = tid >> 6;
    float* xo = xT + (size_t)t * KH + (size_t)kc * BB;
    #pragma unroll
    for (int i = 0; i < 16; ++i) {
        const int kl = k0 + (i << 2);
        xo[kl * BB + b] = tile[b][kl];
    }
}

// ---------------- grid barrier: relaxed atomics, ONE buffer_inv per step ----
// All data that races across blocks is written with sc1 stores (store_coh),
// so the only cache maintenance needed is a single acquire fence (buffer_inv)
// per block per step to drop stale L1/L2 copies of the h-buffers.
__device__ inline void grid_barrier(unsigned* gbar, unsigned* groot,
                                    unsigned barIdx, int bid)
{
    __syncthreads();   // rendezvous + drains every wave's vmcnt (h-stores done)
    if (threadIdx.x == 0) {
        const int g = bid & 15;
        const unsigned old = __hip_atomic_fetch_add(
            &gbar[g * 16], 1u, __ATOMIC_RELAXED, __HIP_MEMORY_SCOPE_AGENT);
        if (old == barIdx * 16u + 15u) {
            // dependency on `old` orders this after the gbar add completed
            __hip_atomic_fetch_add(groot, 1u, __ATOMIC_RELAXED,
                                   __HIP_MEMORY_SCOPE_AGENT);
        }
        const unsigned tgt = (barIdx + 1u) * 16u;
        while (__hip_atomic_load(groot, __ATOMIC_RELAXED,
                                 __HIP_MEMORY_SCOPE_AGENT) < tgt) {
            __builtin_amdgcn_s_sleep(1);
        }
        // single L1+L2 invalidate for this CU/XCD, per step
        __builtin_amdgcn_fence(__ATOMIC_ACQUIRE, "agent");
    }
    __syncthreads();
}

// ---------------- phase B: pipelined persistent scan ------------------------
// 256 blocks x 8 waves. Block owns 2 hidden units per layer (8 gate rows each).
// Step s: L0 computes t0=s (s<TT), L1 computes t1=s-1 (s>=1).
// Wave roles (grp=w>>1): 0: L0 in-proj (xT), 1: L0 recur (h0buf),
//                        2: L1 in-proj (h0buf), 3: L1 recur (h1buf).
// kbase=(w&1)*256. Wave 0 does L0 gate math, wave 1 does L1 gate math.
extern "C" __global__ void __launch_bounds__(NTHR)
lstm_scan(const float* __restrict__ h0,
          const float* __restrict__ c0,
          const float* __restrict__ Wih,
          const float* __restrict__ Whh,
          const float* __restrict__ bih,
          const float* __restrict__ bhh,
          const float* __restrict__ xT,
          float* __restrict__ out,
          float* __restrict__ h0buf,   // [2][512][64]
          float* __restrict__ h1buf,   // [2][512][64]
          unsigned* __restrict__ gbar,
          unsigned* __restrict__ groot)
{
    __shared__ float red[8][8][64];

    const int tid  = threadIdx.x;
    const int lane = tid & 63;                                   // batch
    const int w    = __builtin_amdgcn_readfirstlane(tid >> 6);   // wave 0..7
    const int bid  = blockIdx.x;
    const int hk0  = bid << 1;

    const int kbase = (w & 1) << 8;
    const int grp   = w >> 1;

    const float* Wbase;
    if      (grp == 0) Wbase = Wih;
    else if (grp == 1) Wbase = Whh;
    else if (grp == 2) Wbase = Wih + (size_t)G4 * HH;
    else               Wbase = Whh + (size_t)G4 * HH;

    const float* Wrow[8];
    #pragma unroll
    for (int rr = 0; rr < 8; ++rr) {
        const int row = ((rr >> 1) << 9) + hk0 + (rr & 1);
        Wrow[rr] = Wbase + (size_t)row * HH + kbase;
    }

    float creg[2] = {0.f, 0.f};  // wave0: L0 c-state; wave1: L1 c-state
    float bs[8];
    if (w == 0) {
        #pragma unroll
        for (int u = 0; u < 2; ++u) {
            const int hk = hk0 + u;
            store_coh(&h0buf[hk * BB + lane], h0[(size_t)lane * HH + hk]);
            creg[u] = c0[(size_t)lane * HH + hk];
        }
        #pragma unroll
        for (int rr = 0; rr < 8; ++rr) {
            const int row = ((rr >> 1) << 9) + hk0 + (rr & 1);
            bs[rr] = bih[row] + bhh[row];
        }
    } else if (w == 1) {
        #pragma unroll
        for (int u = 0; u < 2; ++u) {
            const int hk = hk0 + u;
            store_coh(&h1buf[hk * BB + lane], h0[(size_t)(BB + lane) * HH + hk]);
            creg[u] = c0[(size_t)(BB + lane) * HH + hk];
        }
        #pragma unroll
        for (int rr = 0; rr < 8; ++rr) {
            const int row = ((rr >> 1) << 9) + hk0 + (rr & 1);
            bs[rr] = bih[G4 + row] + bhh[G4 + row];
        }
    }

    unsigned barIdx = 0;
    grid_barrier(gbar, groot, barIdx, bid); ++barIdx;

    for (int s = 0; s <= TT; ++s) {
        const float* act;
        if (grp == 0) {
            const int t0 = (s < TT) ? s : (TT - 1);
            act = xT + (size_t)t0 * KH + (size_t)kbase * BB;
        } else if (grp <= 2) {
            act = h0buf + (size_t)(s & 1) * KH + (size_t)kbase * BB;
        } else {
            act = h1buf + (size_t)((s + 1) & 1) * KH + (size_t)kbase * BB;
        }

        float acc[8];
        #pragma unroll
        for (int rr = 0; rr < 8; ++rr) acc[rr] = 0.0f;

        #pragma unroll 2
        for (int j = 0; j < 256; j += 4) {
            const float a0 = act[(j + 0) * BB + lane];
            const float a1 = act[(j + 1) * BB + lane];
            const float a2 = act[(j + 2) * BB + lane];
            const float a3 = act[(j + 3) * BB + lane];
            #pragma unroll
            for (int rr = 0; rr < 8; ++rr) {
                const float4 wv = *(const float4*)(Wrow[rr] + j);
                acc[rr] = fmaf(a3, wv.w,
                           fmaf(a2, wv.z,
                            fmaf(a1, wv.y,
                             fmaf(a0, wv.x, acc[rr]))));
            }
        }

        #pragma unroll
        for (int rr = 0; rr < 8; ++rr) red[w][rr][lane] = acc[rr];
        __syncthreads();

        if (w == 0) {
            if (s < TT) {   // layer 0, t0 = s
                float g[8];
                #pragma unroll
                for (int rr = 0; rr < 8; ++rr)
                    g[rr] = bs[rr] + red[0][rr][lane] + red[1][rr][lane]
                                   + red[2][rr][lane] + red[3][rr][lane];
                #pragma unroll
                for (int u = 0; u < 2; ++u) {
                    const float ig = sigm(g[0 + u]);
                    const float fg = sigm(g[2 + u]);
                    const float gg = tanh_fast(g[4 + u]);
                    const float og = sigm(g[6 + u]);
                    const float cn = fg * creg[u] + ig * gg;
                    const float hn = og * tanh_fast(cn);
                    creg[u] = cn;
                    const int hk = hk0 + u;
                    store_coh(&h0buf[(size_t)((s + 1) & 1) * KH + hk * BB + lane], hn);
                    if (s == TT - 1) {
                        out[HN_OFF + (size_t)lane * HH + hk] = hn;
                        out[CN_OFF + (size_t)lane * HH + hk] = cn;
                    }
                }
            }
        } else if (w == 1) {
            if (s >= 1) {   // layer 1, t1 = s-1
                const int t1 = s - 1;
                float g[8];
                #pragma unroll
                for (int rr = 0; rr < 8; ++rr)
                    g[rr] = bs[rr] + red[4][rr][lane] + red[5][rr][lane]
                                   + red[6][rr][lane] + red[7][rr][lane];
                #pragma unroll
                for (int u = 0; u < 2; ++u) {
                    const float ig = sigm(g[0 + u]);
                    const float fg = sigm(g[2 + u]);
                    const float gg = tanh_fast(g[4 + u]);
                    const float og = sigm(g[6 + u]);
                    const float cn = fg * creg[u] + ig * gg;
                    const float hn = og * tanh_fast(cn);
                    creg[u] = cn;
                    const int hk = hk0 + u;
                    store_coh(&h1buf[(size_t)(s & 1) * KH + hk * BB + lane], hn);
                    out[(size_t)t1 * BB * HH + (size_t)lane * HH + hk] = hn;
                    if (t1 == TT - 1) {
                        out[HN_OFF + (size_t)(BB + lane) * HH + hk] = hn;
                        out[CN_OFF + (size_t)(BB + lane) * HH + hk] = cn;
                    }
                }
            }
        }
        grid_barrier(gbar, groot, barIdx, bid); ++barIdx;
    }
}

// ---------------------------------------------------------------------------
extern "C" void kernel_launch(void* const* d_in, const int* in_sizes, int n_in,
                              void* d_out, int out_size, void* d_ws, size_t ws_size,
                              hipStream_t stream)
{
    (void)in_sizes; (void)n_in; (void)out_size; (void)ws_size;
    const float* x   = (const float*)d_in[0];
    const float* h0  = (const float*)d_in[1];
    const float* c0  = (const float*)d_in[2];
    const float* Wih = (const float*)d_in[3];
    const float* Whh = (const float*)d_in[4];
    const float* bih = (const float*)d_in[5];
    const float* bhh = (const float*)d_in[6];
    float* out = (float*)d_out;

    // ws: xT [T][512][64] (128 MB) | h0buf [2][512][64] | h1buf | barrier ctrs
    float* xT    = (float*)d_ws;
    float* h0buf = xT + (size_t)TT * KH;
    float* h1buf = h0buf + (size_t)2 * KH;
    unsigned* gbar  = (unsigned*)(h1buf + (size_t)2 * KH);
    unsigned* groot = gbar + 256;

    hipMemsetAsync(gbar, 0, (256 + 64) * sizeof(unsigned), stream);

    xpose<<<dim3(TT, 8), 256, 0, stream>>>(x, xT);

    void* args[] = {(void*)&h0, (void*)&c0, (void*)&Wih, (void*)&Whh,
                    (void*)&bih, (void*)&bhh, (void*)&xT, (void*)&out,
                    (void*)&h0buf, (void*)&h1buf, (void*)&gbar, (void*)&groot};
    hipLaunchCooperativeKernel((void*)lstm_scan, dim3(NBLK), dim3(NTHR),
                               args, 0, stream);
}